// Round 17
// baseline (146.730 us; speedup 1.0000x reference)
//
#include <hip/hip_runtime.h>
#include <hip/hip_bf16.h>

#define BINS 100
#define DIM 768
#define TPB 64        // tokens per window
#define NTHREADS 256
#define KPAD 128      // BINS padded to MFMA K multiple
#define PITCH 136     // ushort pitch for wbf rows: 272B, 16B-aligned
#define WPB 4         // windows per block (persistent-style sweep)

// workspace byte offsets
#define OFF_ET    0        // ushort[768*128] = 196608 B
#define OFF_P     196608   // float[100] (512 B reserved)
#define OFF_Q     197120   // float[100] (512 B reserved)
#define OFF_RARE  197632   // float4[104] = 1664 B (2048 reserved)
#define OFF_R     199680   // int (64 B reserved)
#define OFF_W2PT  199744   // float[100*100] = 40000 B (end 239744)

typedef __attribute__((ext_vector_type(8))) short bf16x8;
typedef __attribute__((ext_vector_type(4))) float f32x4;
typedef __attribute__((ext_vector_type(16))) float f32x16;

__device__ __forceinline__ unsigned short f2bf(float x) {
    __hip_bfloat16 h = __float2bfloat16(x);
    return *reinterpret_cast<unsigned short*>(&h);
}
__device__ __forceinline__ float bfrt(float x) {   // bf16 round-trip (RNE)
    return __bfloat162float(__float2bfloat16(x));
}
__device__ __forceinline__ f32x4 bfrt4(f32x4 v) {
    f32x4 r;
    r.x = bfrt(v.x); r.y = bfrt(v.y); r.z = bfrt(v.z); r.w = bfrt(v.w);
    return r;
}

// grid = DIM + BINS blocks x 128 threads.
// Blocks [0,DIM): transpose emb -> bf16 ET (one d-column each).
// Blocks [DIM, DIM+BINS): bin j = bid-DIM. PARALLEL build of P[j], Q[j],
// w2pT[:,j], rare[rank(j)] (r16: replaced serial tail, -7 us).
__global__ void prep(const float* __restrict__ emb,
                     const float* __restrict__ w1,
                     const float* __restrict__ b1,
                     const float* __restrict__ w2,
                     const float* __restrict__ b2,
                     unsigned char* __restrict__ ws)
{
    const int bid = blockIdx.x;
    const int tid = threadIdx.x;
    if (bid < DIM) {
        unsigned short* et = (unsigned short*)(ws + OFF_ET);
        float v = (tid < BINS) ? emb[(long)tid * DIM + bid] : 0.f;
        et[bid * KPAD + tid] = f2bf(v);
        return;
    }
    const int j = bid - DIM;           // 0..BINS-1
    float* Pv   = (float*)(ws + OFF_P);
    float* Qv   = (float*)(ws + OFF_Q);
    f32x4* rare = (f32x4*)(ws + OFF_RARE);
    int*   Rp   = (int*)  (ws + OFF_R);
    float* w2pT = (float*)(ws + OFF_W2PT);

    __shared__ float pl[128], ql[128], tl[128];
    __shared__ float redP[128], redQ[128];

    if (tid < BINS) {
        float w = w1[tid], b = b1[tid];
        // branch taken as x -> +inf (the "common" branch for x in [0,10])
        float f = (w > 0.f || (w == 0.f && b > 0.f)) ? 1.f : 0.1f;
        pl[tid] = w * f;
        ql[tid] = b * f;
        tl[tid] = (w != 0.f) ? (-b / w) : -1.f;   // breakpoint; w==0 never flips
    } else {
        pl[tid] = 0.f; ql[tid] = 0.f; tl[tid] = -1.f;
    }
    __syncthreads();

    // parallel over k = tid: coalesced row read of w2[j][:]
    float pP = 0.f, pQ = 0.f;
    if (tid < BINS) {
        float w = w2[j * BINS + tid];
        pP = w * pl[tid];
        pQ = w * ql[tid];
        // transposed (+I): row k contiguous in j -> coalesced correction reads
        w2pT[tid * BINS + j] = w + (j == tid ? 1.f : 0.f);
    }
    redP[tid] = pP; redQ[tid] = pQ;
    __syncthreads();
    #pragma unroll
    for (int sft = 64; sft > 0; sft >>= 1) {
        if (tid < sft) { redP[tid] += redP[tid + sft]; redQ[tid] += redQ[tid + sft]; }
        __syncthreads();
    }
    if (tid == 0) {
        Pv[j] = pl[j] + redP[0];              // alpha=1 direct term + w2 row dot
        Qv[j] = ql[j] + b2[j] + redQ[0];
    }

    // rank(j) among thresholds, descending (ties by index): parallel predicate
    const float tj = tl[j];
    float pr = 0.f;
    if (tid < BINS) {
        float t2 = tl[tid];
        pr = (t2 > tj || (t2 == tj && tid < j)) ? 1.f : 0.f;
    }
    __syncthreads();
    redP[tid] = pr;
    __syncthreads();
    #pragma unroll
    for (int sft = 64; sft > 0; sft >>= 1) {
        if (tid < sft) redP[tid] += redP[tid + sft];
        __syncthreads();
    }
    if (tid == 0) {
        int rank = (int)redP[0];
        f32x4 e;
        e.x = tj; e.y = w1[j]; e.z = b1[j];
        e.w = __int_as_float(j);
        rare[rank] = e;
    }

    if (j == 0) {   // R (count of positive thresholds) + sentinel
        float pp = (tid < BINS && tl[tid] > 0.f) ? 1.f : 0.f;
        __syncthreads();
        redQ[tid] = pp;
        __syncthreads();
        #pragma unroll
        for (int sft = 64; sft > 0; sft >>= 1) {
            if (tid < sft) redQ[tid] += redQ[tid + sft];
            __syncthreads();
        }
        if (tid == 0) {
            *Rp = (int)redQ[0];
            f32x4 s; s.x = -1e30f; s.y = 0.f; s.z = 0.f; s.w = __int_as_float(0);
            rare[BINS] = s;
        }
    }
}

// Persistent-style blocks: grid = nwin/WPB; block b processes windows
// b, b+grid, b+2*grid, ... At sweep-step i ALL resident blocks write the
// contiguous region [i*grid, (i+1)*grid) * 192KB -> dense monotone advancing
// write front (the fill kernel's structural property). pe/me loads + bf16
// rounding hoisted out of the window loop.
__global__ __launch_bounds__(NTHREADS, 4)
void ead_kernel(const float* __restrict__ gene,
                const int*   __restrict__ pad_mask,
                const int*   __restrict__ masked_mask,
                const unsigned short* __restrict__ et,
                const float* __restrict__ Pv,
                const float* __restrict__ Qv,
                const f32x4* __restrict__ rare,
                const int*   __restrict__ Rp,
                const float* __restrict__ w2pT,
                const float* __restrict__ pad_emb,
                const float* __restrict__ mask_emb,
                float* __restrict__ out,
                int nwin, int T)
{
    __shared__ unsigned short wbf[TPB][PITCH]; // bf16 softmax weights, K-padded
    __shared__ float xs[TPB];
    __shared__ short surv[TPB];
    __shared__ short olist[TPB];   // row | (is_mask << 8)
    __shared__ int Ssh, Osh;

    const int tid  = threadIdx.x;
    const int lane = tid & 63;
    const int wave = tid >> 6;

    // hoisted: pad/mask row patterns, bf16-rounded, once per block
    const f32x4* pe = (const f32x4*)pad_emb;
    const f32x4* me = (const f32x4*)mask_emb;
    const f32x4 p0 = bfrt4(pe[lane]), p1 = bfrt4(pe[lane + 64]), p2 = bfrt4(pe[lane + 128]);
    const f32x4 m0 = bfrt4(me[lane]), m1 = bfrt4(me[lane + 64]), m2 = bfrt4(me[lane + 128]);

    for (int w = (int)blockIdx.x; w < nwin; w += (int)gridDim.x) {
        const long t0 = (long)w * TPB;
        const int nvalid = min(TPB, (int)(T - t0));

        __syncthreads();   // LDS WAR: prior window's MFMA reads done before rewrite

        // ---- step 1: masks, survivor + override compaction (wave 0) ----
        if (wave == 0) {
            int o = 3; // out-of-range: neither computed nor written
            if (lane < nvalid) {
                int pm  = pad_mask[t0 + lane];
                int msk = masked_mask[t0 + lane];
                o = msk ? 2 : (pm ? 1 : 0);
                xs[lane] = gene[t0 + lane];
            }
            unsigned long long bs = __ballot(o == 0);
            unsigned long long bo = __ballot(o == 1 || o == 2);
            int si = __popcll(bs & ((1ull << lane) - 1ull));
            int oi = __popcll(bo & ((1ull << lane) - 1ull));
            if (o == 0) surv[si] = (short)lane;
            if (o == 1 || o == 2) olist[oi] = (short)(lane | ((o == 2) ? 256 : 0));
            if (lane == 0) { Ssh = __popcll(bs); Osh = __popcll(bo); }
        }
        __syncthreads();
        const int S = Ssh, O = Osh;

        // ---- step 1.5: override rows, row-per-wave, NT streaming stores ----
        // (r12 A/B: NT = -28 us; keeps override lines out of L2.)
        for (int i = wave; i < O; i += 4) {
            int e = olist[i];
            int row = e & 63;
            bool mm = (e & 256) != 0;
            f32x4* orow = (f32x4*)(out + (t0 + row) * (long)DIM);
            __builtin_nontemporal_store(mm ? m0 : p0, orow + lane);
            __builtin_nontemporal_store(mm ? m1 : p1, orow + lane + 64);
            __builtin_nontemporal_store(mm ? m2 : p2, orow + lane + 128);
        }

        // ---- steps 2-4: v3 = x*P + Q + rare corrections; softmax -> wbf ----
        {
            int s = wave + 4 * (lane >> 2);
            int part = lane & 3;
            const int j0 = part * 25;
            if (s < S) {
                float x = xs[surv[s]];
                float v3[25];
                #pragma unroll
                for (int i = 0; i < 25; i++)
                    v3[i] = fmaf(x, Pv[j0 + i], Qv[j0 + i]);
                const int R = *Rp;
                for (int idx = 0; idx < R; ++idx) {
                    f32x4 rr = rare[idx];
                    if (rr.x <= x) break;           // sorted desc: rest common
                    float v1 = fmaf(x, rr.y, rr.z);
                    float d = 0.9f * fabsf(v1);     // (f_actual - f_common)*v1
                    int k = __float_as_int(rr.w);
                    const float* wc = w2pT + k * BINS + j0;
                    #pragma unroll
                    for (int i = 0; i < 25; i++)
                        v3[i] = fmaf(wc[i], d, v3[i]);
                }
                float vmax = -1e30f;
                #pragma unroll
                for (int i = 0; i < 25; i++) vmax = fmaxf(vmax, v3[i]);
                vmax = fmaxf(vmax, __shfl_xor(vmax, 1));
                vmax = fmaxf(vmax, __shfl_xor(vmax, 2));
                float sum = 0.f;
                #pragma unroll
                for (int i = 0; i < 25; i++) {
                    v3[i] = __expf(v3[i] - vmax);
                    sum += v3[i];
                }
                sum += __shfl_xor(sum, 1);
                sum += __shfl_xor(sum, 2);
                float inv = 1.f / sum;
                #pragma unroll
                for (int i = 0; i < 25; i++)
                    wbf[s][j0 + i] = f2bf(v3[i] * inv);
                if (part == 3) {
                    #pragma unroll
                    for (int j = BINS; j < KPAD; j += 2)
                        *reinterpret_cast<unsigned int*>(&wbf[s][j]) = 0u;
                }
            }
        }
        __syncthreads();

        // ---- step 5: MFMA 32x32x16: D[slot][d] = W(S x K) · ET^T(K x d) ----
        // C/D layout (verified): col=lane&31, row=(reg&3)+8*(reg>>2)+4*(lane>>5).
        // A,B share k-mapping k = ks*16 + half*8 + j (hw k-perm cancels).
        // One store instruction = 2 rows x 128B fully-covered lines.
        if (S > 0) {
            const int col  = lane & 31;
            const int half = lane >> 5;
            const int nmt = (S > 32) ? 2 : 1;
            for (int mtile = 0; mtile < nmt; mtile++) {
                const unsigned short* arow = &wbf[mtile * 32 + col][half * 8];
                bf16x8 a0 = *(const bf16x8*)(arow);
                bf16x8 a1 = *(const bf16x8*)(arow + 16);
                bf16x8 a2 = *(const bf16x8*)(arow + 32);
                bf16x8 a3 = *(const bf16x8*)(arow + 48);
                bf16x8 a4 = *(const bf16x8*)(arow + 64);
                bf16x8 a5 = *(const bf16x8*)(arow + 80);
                bf16x8 a6 = *(const bf16x8*)(arow + 96);
                bf16x8 a7 = *(const bf16x8*)(arow + 112);
                for (int ct = 0; ct < 6; ct++) {
                    int cbase = (wave * 6 + ct) * 32;
                    const unsigned short* bp = et + (long)(cbase + col) * KPAD + half * 8;
                    f32x16 acc;
                    #pragma unroll
                    for (int r = 0; r < 16; r++) acc[r] = 0.f;
                    acc = __builtin_amdgcn_mfma_f32_32x32x16_bf16(a0, *(const bf16x8*)(bp),       acc, 0, 0, 0);
                    acc = __builtin_amdgcn_mfma_f32_32x32x16_bf16(a1, *(const bf16x8*)(bp + 16),  acc, 0, 0, 0);
                    acc = __builtin_amdgcn_mfma_f32_32x32x16_bf16(a2, *(const bf16x8*)(bp + 32),  acc, 0, 0, 0);
                    acc = __builtin_amdgcn_mfma_f32_32x32x16_bf16(a3, *(const bf16x8*)(bp + 48),  acc, 0, 0, 0);
                    acc = __builtin_amdgcn_mfma_f32_32x32x16_bf16(a4, *(const bf16x8*)(bp + 64),  acc, 0, 0, 0);
                    acc = __builtin_amdgcn_mfma_f32_32x32x16_bf16(a5, *(const bf16x8*)(bp + 80),  acc, 0, 0, 0);
                    acc = __builtin_amdgcn_mfma_f32_32x32x16_bf16(a6, *(const bf16x8*)(bp + 96),  acc, 0, 0, 0);
                    acc = __builtin_amdgcn_mfma_f32_32x32x16_bf16(a7, *(const bf16x8*)(bp + 112), acc, 0, 0, 0);
                    #pragma unroll
                    for (int r = 0; r < 16; r++) {
                        int row = (r & 3) + 8 * (r >> 2) + 4 * half + mtile * 32;
                        if (row < S) {
                            int tkn = surv[row];
                            out[(t0 + tkn) * (long)DIM + cbase + col] = acc[r];
                        }
                    }
                }
            }
        }
    }
}

extern "C" void kernel_launch(void* const* d_in, const int* in_sizes, int n_in,
                              void* d_out, int out_size, void* d_ws, size_t ws_size,
                              hipStream_t stream) {
    const float* gene  = (const float*)d_in[0];
    const int*   pm    = (const int*)  d_in[1];
    const int*   mm    = (const int*)  d_in[2];
    const float* w1    = (const float*)d_in[3];
    const float* b1    = (const float*)d_in[4];
    const float* w2    = (const float*)d_in[5];
    const float* b2    = (const float*)d_in[6];
    const float* emb   = (const float*)d_in[7];
    const float* pade  = (const float*)d_in[8];
    const float* maske = (const float*)d_in[9];
    float* out = (float*)d_out;
    unsigned char* ws = (unsigned char*)d_ws;

    int T = in_sizes[0];                          // 8 * 19264 = 154112 tokens
    int nwin = (T + TPB - 1) / TPB;               // 2408 output windows
    int grid = (nwin + WPB - 1) / WPB;            // 602 persistent-style blocks

    hipLaunchKernelGGL(prep, dim3(DIM + BINS), dim3(128), 0, stream,
                       emb, w1, b1, w2, b2, ws);
    hipLaunchKernelGGL(ead_kernel, dim3(grid), dim3(NTHREADS), 0, stream,
                       gene, pm, mm,
                       (const unsigned short*)(ws + OFF_ET),
                       (const float*)(ws + OFF_P),
                       (const float*)(ws + OFF_Q),
                       (const f32x4*)(ws + OFF_RARE),
                       (const int*)(ws + OFF_R),
                       (const float*)(ws + OFF_W2PT),
                       pade, maske, out, nwin, T);
}

// Round 18
// 145.955 us; speedup vs baseline: 1.0053x; 1.0053x over previous
//
#include <hip/hip_runtime.h>
#include <hip/hip_bf16.h>

#define BINS 100
#define DIM 768
#define TPB 64        // tokens per block
#define NTHREADS 256
#define KPAD 128      // BINS padded to MFMA K multiple
#define PITCH 136     // ushort pitch for wbf rows: 272B, 16B-aligned

// workspace byte offsets
#define OFF_ET    0        // ushort[768*128] = 196608 B
#define OFF_P     196608   // float[100] (512 B reserved)
#define OFF_Q     197120   // float[100] (512 B reserved)
#define OFF_RARE  197632   // float4[104] = 1664 B (2048 reserved)
#define OFF_R     199680   // int (64 B reserved)
#define OFF_W2PT  199744   // float[100*100] = 40000 B (end 239744)

typedef __attribute__((ext_vector_type(8))) short bf16x8;
typedef __attribute__((ext_vector_type(4))) float f32x4;
typedef __attribute__((ext_vector_type(16))) float f32x16;

__device__ __forceinline__ unsigned short f2bf(float x) {
    __hip_bfloat16 h = __float2bfloat16(x);
    return *reinterpret_cast<unsigned short*>(&h);
}
__device__ __forceinline__ float bfrt(float x) {   // bf16 round-trip (RNE)
    return __bfloat162float(__float2bfloat16(x));
}
__device__ __forceinline__ f32x4 bfrt4(f32x4 v) {
    f32x4 r;
    r.x = bfrt(v.x); r.y = bfrt(v.y); r.z = bfrt(v.z); r.w = bfrt(v.w);
    return r;
}

// grid = DIM + BINS blocks x 128 threads.
// Blocks [0,DIM): transpose emb -> bf16 ET (one d-column each).
// Blocks [DIM, DIM+BINS): bin j = bid-DIM. PARALLEL build of P[j], Q[j],
// w2pT[:,j], rare[rank(j)] (r16: replaced serial tail, -7 us).
__global__ void prep(const float* __restrict__ emb,
                     const float* __restrict__ w1,
                     const float* __restrict__ b1,
                     const float* __restrict__ w2,
                     const float* __restrict__ b2,
                     unsigned char* __restrict__ ws)
{
    const int bid = blockIdx.x;
    const int tid = threadIdx.x;
    if (bid < DIM) {
        unsigned short* et = (unsigned short*)(ws + OFF_ET);
        float v = (tid < BINS) ? emb[(long)tid * DIM + bid] : 0.f;
        et[bid * KPAD + tid] = f2bf(v);
        return;
    }
    const int j = bid - DIM;           // 0..BINS-1
    float* Pv   = (float*)(ws + OFF_P);
    float* Qv   = (float*)(ws + OFF_Q);
    f32x4* rare = (f32x4*)(ws + OFF_RARE);
    int*   Rp   = (int*)  (ws + OFF_R);
    float* w2pT = (float*)(ws + OFF_W2PT);

    __shared__ float pl[128], ql[128], tl[128];
    __shared__ float redP[128], redQ[128];

    if (tid < BINS) {
        float w = w1[tid], b = b1[tid];
        // branch taken as x -> +inf (the "common" branch for x in [0,10])
        float f = (w > 0.f || (w == 0.f && b > 0.f)) ? 1.f : 0.1f;
        pl[tid] = w * f;
        ql[tid] = b * f;
        tl[tid] = (w != 0.f) ? (-b / w) : -1.f;   // breakpoint; w==0 never flips
    } else {
        pl[tid] = 0.f; ql[tid] = 0.f; tl[tid] = -1.f;
    }
    __syncthreads();

    // parallel over k = tid: coalesced row read of w2[j][:]
    float pP = 0.f, pQ = 0.f;
    if (tid < BINS) {
        float w = w2[j * BINS + tid];
        pP = w * pl[tid];
        pQ = w * ql[tid];
        // transposed (+I): row k contiguous in j -> coalesced correction reads
        w2pT[tid * BINS + j] = w + (j == tid ? 1.f : 0.f);
    }
    redP[tid] = pP; redQ[tid] = pQ;
    __syncthreads();
    #pragma unroll
    for (int sft = 64; sft > 0; sft >>= 1) {
        if (tid < sft) { redP[tid] += redP[tid + sft]; redQ[tid] += redQ[tid + sft]; }
        __syncthreads();
    }
    if (tid == 0) {
        Pv[j] = pl[j] + redP[0];              // alpha=1 direct term + w2 row dot
        Qv[j] = ql[j] + b2[j] + redQ[0];
    }

    // rank(j) among thresholds, descending (ties by index): parallel predicate
    const float tj = tl[j];
    float pr = 0.f;
    if (tid < BINS) {
        float t2 = tl[tid];
        pr = (t2 > tj || (t2 == tj && tid < j)) ? 1.f : 0.f;
    }
    __syncthreads();
    redP[tid] = pr;
    __syncthreads();
    #pragma unroll
    for (int sft = 64; sft > 0; sft >>= 1) {
        if (tid < sft) redP[tid] += redP[tid + sft];
        __syncthreads();
    }
    if (tid == 0) {
        int rank = (int)redP[0];
        f32x4 e;
        e.x = tj; e.y = w1[j]; e.z = b1[j];
        e.w = __int_as_float(j);
        rare[rank] = e;
    }

    if (j == 0) {   // R (count of positive thresholds) + sentinel
        float pp = (tid < BINS && tl[tid] > 0.f) ? 1.f : 0.f;
        __syncthreads();
        redQ[tid] = pp;
        __syncthreads();
        #pragma unroll
        for (int sft = 64; sft > 0; sft >>= 1) {
            if (tid < sft) redQ[tid] += redQ[tid + sft];
            __syncthreads();
        }
        if (tid == 0) {
            *Rp = (int)redQ[0];
            f32x4 s; s.x = -1e30f; s.y = 0.f; s.z = 0.f; s.w = __int_as_float(0);
            rare[BINS] = s;
        }
    }
}

// Wave-specialized block (anti-convoy): after one cheap barrier, wave 3 becomes
// a dedicated override-row NT streamer (stores flow continuously; it never
// crosses another barrier -> no vmcnt(0) drain gates it or the others); waves
// 0-2 run MLP (48 slot-handlers) then MFMA (8 d-tiles each), synced among
// THEMSELVES via an LDS flag instead of __syncthreads.
__global__ __launch_bounds__(NTHREADS, 8)
void ead_kernel(const float* __restrict__ gene,
                const int*   __restrict__ pad_mask,
                const int*   __restrict__ masked_mask,
                const unsigned short* __restrict__ et,
                const float* __restrict__ Pv,
                const float* __restrict__ Qv,
                const f32x4* __restrict__ rare,
                const int*   __restrict__ Rp,
                const float* __restrict__ w2pT,
                const float* __restrict__ pad_emb,
                const float* __restrict__ mask_emb,
                float* __restrict__ out,
                int T)
{
    __shared__ unsigned short wbf[TPB][PITCH]; // bf16 softmax weights, K-padded
    __shared__ float xs[TPB];
    __shared__ short surv[TPB];
    __shared__ short olist[TPB];   // row | (is_mask << 8)
    __shared__ int Ssh, Osh;
    __shared__ int mlp_done;

    const int tid  = threadIdx.x;
    const int lane = tid & 63;
    const int wave = tid >> 6;

    // XCD-bijective swizzle: consecutive output regions stay on one XCD's L2.
    const int nblk = (int)gridDim.x;
    const int bid  = (int)blockIdx.x;
    const int wg   = ((nblk & 7) == 0) ? ((bid & 7) * (nblk >> 3) + (bid >> 3))
                                       : bid;
    const long t0  = (long)wg * TPB;
    const int nvalid = min(TPB, (int)(T - t0));

    // ---- step 1: masks, survivor + override compaction (wave 0) ----
    if (wave == 0) {
        int o = 3; // out-of-range: neither computed nor written
        if (lane < nvalid) {
            int pm  = pad_mask[t0 + lane];
            int msk = masked_mask[t0 + lane];
            o = msk ? 2 : (pm ? 1 : 0);
            xs[lane] = gene[t0 + lane];
        }
        unsigned long long bs = __ballot(o == 0);
        unsigned long long bo = __ballot(o == 1 || o == 2);
        int si = __popcll(bs & ((1ull << lane) - 1ull));
        int oi = __popcll(bo & ((1ull << lane) - 1ull));
        if (o == 0) surv[si] = (short)lane;
        if (o == 1 || o == 2) olist[oi] = (short)(lane | ((o == 2) ? 256 : 0));
        if (lane == 0) { Ssh = __popcll(bs); Osh = __popcll(bo); mlp_done = 0; }
    }
    __syncthreads();   // ONLY block-wide barrier; no stores outstanding -> cheap
    const int S = Ssh, O = Osh;

    if (wave == 3) {
        // ============ override streamer wave: pure NT store stream ============
        // (r12 A/B: NT = -28 us.) olist preloaded lane-parallel, shfl-broadcast.
        int eall = (lane < O) ? (int)olist[lane] : 0;
        const f32x4* pe = (const f32x4*)pad_emb;
        const f32x4* me = (const f32x4*)mask_emb;
        f32x4 p0 = bfrt4(pe[lane]), p1 = bfrt4(pe[lane + 64]), p2 = bfrt4(pe[lane + 128]);
        f32x4 m0 = bfrt4(me[lane]), m1 = bfrt4(me[lane + 64]), m2 = bfrt4(me[lane + 128]);
        for (int i = 0; i < O; i++) {
            int e = __shfl(eall, i);
            int row = e & 63;
            bool mm = (e & 256) != 0;
            f32x4* orow = (f32x4*)(out + (t0 + row) * (long)DIM);
            __builtin_nontemporal_store(mm ? m0 : p0, orow + lane);
            __builtin_nontemporal_store(mm ? m1 : p1, orow + lane + 64);
            __builtin_nontemporal_store(mm ? m2 : p2, orow + lane + 128);
        }
        return;   // s_endpgm drains stores while other waves compute
    }

    // ============ compute waves 0-2 ============
    // ---- MLP + softmax: 48 slot-handlers (wave + 3*quad), stride-48 overflow ----
    {
        int q = lane >> 2;
        int part = lane & 3;
        const int j0 = part * 25;
        for (int s = wave + 3 * q; s < S; s += 48) {
            float x = xs[surv[s]];
            float v3[25];
            #pragma unroll
            for (int i = 0; i < 25; i++)
                v3[i] = fmaf(x, Pv[j0 + i], Qv[j0 + i]);
            const int R = *Rp;
            for (int idx = 0; idx < R; ++idx) {
                f32x4 rr = rare[idx];
                if (rr.x <= x) break;           // sorted desc: rest are common
                float v1 = fmaf(x, rr.y, rr.z);
                float d = 0.9f * fabsf(v1);     // (f_actual - f_common)*v1
                int k = __float_as_int(rr.w);
                const float* wc = w2pT + k * BINS + j0;
                #pragma unroll
                for (int i = 0; i < 25; i++)
                    v3[i] = fmaf(wc[i], d, v3[i]);
            }
            float vmax = -1e30f;
            #pragma unroll
            for (int i = 0; i < 25; i++) vmax = fmaxf(vmax, v3[i]);
            vmax = fmaxf(vmax, __shfl_xor(vmax, 1));
            vmax = fmaxf(vmax, __shfl_xor(vmax, 2));
            float sum = 0.f;
            #pragma unroll
            for (int i = 0; i < 25; i++) {
                v3[i] = __expf(v3[i] - vmax);
                sum += v3[i];
            }
            sum += __shfl_xor(sum, 1);
            sum += __shfl_xor(sum, 2);
            float inv = 1.f / sum;
            #pragma unroll
            for (int i = 0; i < 25; i++)
                wbf[s][j0 + i] = f2bf(v3[i] * inv);
            if (part == 3) {
                #pragma unroll
                for (int j = BINS; j < KPAD; j += 2)
                    *reinterpret_cast<unsigned int*>(&wbf[s][j]) = 0u;
            }
        }
    }
    // ---- 3-wave LDS flag sync (wave 3 excluded; no vmcnt(0) barrier drain) ----
    __threadfence_block();
    if (lane == 0) atomicAdd(&mlp_done, 1);
    {
        volatile int* vd = &mlp_done;
        while (*vd < 3) __builtin_amdgcn_s_sleep(2);
    }
    __threadfence_block();

    // ---- MFMA 32x32x16: D[slot][d] = W(S x K) · ET^T(K x d) ----
    // C/D layout (verified): col=lane&31, row=(reg&3)+8*(reg>>2)+4*(lane>>5).
    // A,B share k-mapping k = ks*16 + half*8 + j (hw k-perm cancels).
    // One store instruction = 2 rows x 128B fully-covered lines.
    // Waves 0-2 cover 8 d-tiles each (contiguous 256-float span per wave).
    if (S > 0) {
        const int col  = lane & 31;
        const int half = lane >> 5;
        const int nmt = (S > 32) ? 2 : 1;
        for (int mtile = 0; mtile < nmt; mtile++) {
            const unsigned short* arow = &wbf[mtile * 32 + col][half * 8];
            bf16x8 a0 = *(const bf16x8*)(arow);
            bf16x8 a1 = *(const bf16x8*)(arow + 16);
            bf16x8 a2 = *(const bf16x8*)(arow + 32);
            bf16x8 a3 = *(const bf16x8*)(arow + 48);
            bf16x8 a4 = *(const bf16x8*)(arow + 64);
            bf16x8 a5 = *(const bf16x8*)(arow + 80);
            bf16x8 a6 = *(const bf16x8*)(arow + 96);
            bf16x8 a7 = *(const bf16x8*)(arow + 112);
            for (int ct = 0; ct < 8; ct++) {
                int cbase = (wave * 8 + ct) * 32;
                const unsigned short* bp = et + (long)(cbase + col) * KPAD + half * 8;
                f32x16 acc;
                #pragma unroll
                for (int r = 0; r < 16; r++) acc[r] = 0.f;
                acc = __builtin_amdgcn_mfma_f32_32x32x16_bf16(a0, *(const bf16x8*)(bp),       acc, 0, 0, 0);
                acc = __builtin_amdgcn_mfma_f32_32x32x16_bf16(a1, *(const bf16x8*)(bp + 16),  acc, 0, 0, 0);
                acc = __builtin_amdgcn_mfma_f32_32x32x16_bf16(a2, *(const bf16x8*)(bp + 32),  acc, 0, 0, 0);
                acc = __builtin_amdgcn_mfma_f32_32x32x16_bf16(a3, *(const bf16x8*)(bp + 48),  acc, 0, 0, 0);
                acc = __builtin_amdgcn_mfma_f32_32x32x16_bf16(a4, *(const bf16x8*)(bp + 64),  acc, 0, 0, 0);
                acc = __builtin_amdgcn_mfma_f32_32x32x16_bf16(a5, *(const bf16x8*)(bp + 80),  acc, 0, 0, 0);
                acc = __builtin_amdgcn_mfma_f32_32x32x16_bf16(a6, *(const bf16x8*)(bp + 96),  acc, 0, 0, 0);
                acc = __builtin_amdgcn_mfma_f32_32x32x16_bf16(a7, *(const bf16x8*)(bp + 112), acc, 0, 0, 0);
                #pragma unroll
                for (int r = 0; r < 16; r++) {
                    int row = (r & 3) + 8 * (r >> 2) + 4 * half + mtile * 32;
                    if (row < S) {
                        int tkn = surv[row];
                        out[(t0 + tkn) * (long)DIM + cbase + col] = acc[r];
                    }
                }
            }
        }
    }
}

extern "C" void kernel_launch(void* const* d_in, const int* in_sizes, int n_in,
                              void* d_out, int out_size, void* d_ws, size_t ws_size,
                              hipStream_t stream) {
    const float* gene  = (const float*)d_in[0];
    const int*   pm    = (const int*)  d_in[1];
    const int*   mm    = (const int*)  d_in[2];
    const float* w1    = (const float*)d_in[3];
    const float* b1    = (const float*)d_in[4];
    const float* w2    = (const float*)d_in[5];
    const float* b2    = (const float*)d_in[6];
    const float* emb   = (const float*)d_in[7];
    const float* pade  = (const float*)d_in[8];
    const float* maske = (const float*)d_in[9];
    float* out = (float*)d_out;
    unsigned char* ws = (unsigned char*)d_ws;

    int T = in_sizes[0];                          // 8 * 19264 = 154112 tokens
    int nblk = (T + TPB - 1) / TPB;               // 2408 (divisible by 8)

    hipLaunchKernelGGL(prep, dim3(DIM + BINS), dim3(128), 0, stream,
                       emb, w1, b1, w2, b2, ws);
    hipLaunchKernelGGL(ead_kernel, dim3(nblk), dim3(NTHREADS), 0, stream,
                       gene, pm, mm,
                       (const unsigned short*)(ws + OFF_ET),
                       (const float*)(ws + OFF_P),
                       (const float*)(ws + OFF_Q),
                       (const f32x4*)(ws + OFF_RARE),
                       (const int*)(ws + OFF_R),
                       (const float*)(ws + OFF_W2PT),
                       pade, maske, out, T);
}

// Round 19
// 138.407 us; speedup vs baseline: 1.0601x; 1.0545x over previous
//
#include <hip/hip_runtime.h>
#include <hip/hip_bf16.h>

#define BINS 100
#define DIM 768
#define TPB 64        // tokens per block
#define NTHREADS 256
#define KPAD 128      // BINS padded to MFMA K multiple
#define PITCH 136     // ushort pitch for wbf rows: 272B, 16B-aligned

// workspace byte offsets
#define OFF_ET    0        // ushort[768*128] = 196608 B
#define OFF_P     196608   // float[100] (512 B reserved)
#define OFF_Q     197120   // float[100] (512 B reserved)
#define OFF_RARE  197632   // float4[104] = 1664 B (2048 reserved)
#define OFF_R     199680   // int (64 B reserved)
#define OFF_W2PT  199744   // float[100*100] = 40000 B (end 239744)

typedef __attribute__((ext_vector_type(8))) short bf16x8;
typedef __attribute__((ext_vector_type(4))) float f32x4;
typedef __attribute__((ext_vector_type(16))) float f32x16;

__device__ __forceinline__ unsigned short f2bf(float x) {
    __hip_bfloat16 h = __float2bfloat16(x);
    return *reinterpret_cast<unsigned short*>(&h);
}
__device__ __forceinline__ float bfrt(float x) {   // bf16 round-trip (RNE)
    return __bfloat162float(__float2bfloat16(x));
}
__device__ __forceinline__ f32x4 bfrt4(f32x4 v) {
    f32x4 r;
    r.x = bfrt(v.x); r.y = bfrt(v.y); r.z = bfrt(v.z); r.w = bfrt(v.w);
    return r;
}

// grid = DIM + BINS blocks x 128 threads.
// Blocks [0,DIM): transpose emb -> bf16 ET (one d-column each).
// Blocks [DIM, DIM+BINS): bin j = bid-DIM. PARALLEL build of P[j], Q[j],
// w2pT[:,j], rare[rank(j)] (r16: replaced serial tail, -7 us).
__global__ void prep(const float* __restrict__ emb,
                     const float* __restrict__ w1,
                     const float* __restrict__ b1,
                     const float* __restrict__ w2,
                     const float* __restrict__ b2,
                     unsigned char* __restrict__ ws)
{
    const int bid = blockIdx.x;
    const int tid = threadIdx.x;
    if (bid < DIM) {
        unsigned short* et = (unsigned short*)(ws + OFF_ET);
        float v = (tid < BINS) ? emb[(long)tid * DIM + bid] : 0.f;
        et[bid * KPAD + tid] = f2bf(v);
        return;
    }
    const int j = bid - DIM;           // 0..BINS-1
    float* Pv   = (float*)(ws + OFF_P);
    float* Qv   = (float*)(ws + OFF_Q);
    f32x4* rare = (f32x4*)(ws + OFF_RARE);
    int*   Rp   = (int*)  (ws + OFF_R);
    float* w2pT = (float*)(ws + OFF_W2PT);

    __shared__ float pl[128], ql[128], tl[128];
    __shared__ float redP[128], redQ[128];

    if (tid < BINS) {
        float w = w1[tid], b = b1[tid];
        // branch taken as x -> +inf (the "common" branch for x in [0,10])
        float f = (w > 0.f || (w == 0.f && b > 0.f)) ? 1.f : 0.1f;
        pl[tid] = w * f;
        ql[tid] = b * f;
        tl[tid] = (w != 0.f) ? (-b / w) : -1.f;   // breakpoint; w==0 never flips
    } else {
        pl[tid] = 0.f; ql[tid] = 0.f; tl[tid] = -1.f;
    }
    __syncthreads();

    // parallel over k = tid: coalesced row read of w2[j][:]
    float pP = 0.f, pQ = 0.f;
    if (tid < BINS) {
        float w = w2[j * BINS + tid];
        pP = w * pl[tid];
        pQ = w * ql[tid];
        // transposed (+I): row k contiguous in j -> coalesced correction reads
        w2pT[tid * BINS + j] = w + (j == tid ? 1.f : 0.f);
    }
    redP[tid] = pP; redQ[tid] = pQ;
    __syncthreads();
    #pragma unroll
    for (int sft = 64; sft > 0; sft >>= 1) {
        if (tid < sft) { redP[tid] += redP[tid + sft]; redQ[tid] += redQ[tid + sft]; }
        __syncthreads();
    }
    if (tid == 0) {
        Pv[j] = pl[j] + redP[0];              // alpha=1 direct term + w2 row dot
        Qv[j] = ql[j] + b2[j] + redQ[0];
    }

    // rank(j) among thresholds, descending (ties by index): parallel predicate
    const float tj = tl[j];
    float pr = 0.f;
    if (tid < BINS) {
        float t2 = tl[tid];
        pr = (t2 > tj || (t2 == tj && tid < j)) ? 1.f : 0.f;
    }
    __syncthreads();
    redP[tid] = pr;
    __syncthreads();
    #pragma unroll
    for (int sft = 64; sft > 0; sft >>= 1) {
        if (tid < sft) redP[tid] += redP[tid + sft];
        __syncthreads();
    }
    if (tid == 0) {
        int rank = (int)redP[0];
        f32x4 e;
        e.x = tj; e.y = w1[j]; e.z = b1[j];
        e.w = __int_as_float(j);
        rare[rank] = e;
    }

    if (j == 0) {   // R (count of positive thresholds) + sentinel
        float pp = (tid < BINS && tl[tid] > 0.f) ? 1.f : 0.f;
        __syncthreads();
        redQ[tid] = pp;
        __syncthreads();
        #pragma unroll
        for (int sft = 64; sft > 0; sft >>= 1) {
            if (tid < sft) redQ[tid] += redQ[tid + sft];
            __syncthreads();
        }
        if (tid == 0) {
            *Rp = (int)redQ[0];
            f32x4 s; s.x = -1e30f; s.y = 0.f; s.z = 0.f; s.w = __int_as_float(0);
            rare[BINS] = s;
        }
    }
}

__global__ __launch_bounds__(NTHREADS, 8)
void ead_kernel(const float* __restrict__ gene,
                const int*   __restrict__ pad_mask,
                const int*   __restrict__ masked_mask,
                const unsigned short* __restrict__ et,
                const float* __restrict__ Pv,
                const float* __restrict__ Qv,
                const f32x4* __restrict__ rare,
                const int*   __restrict__ Rp,
                const float* __restrict__ w2pT,
                const float* __restrict__ pad_emb,
                const float* __restrict__ mask_emb,
                float* __restrict__ out,
                int T)
{
    __shared__ unsigned short wbf[TPB][PITCH]; // bf16 softmax weights, K-padded
    __shared__ float xs[TPB];
    __shared__ short surv[TPB];
    __shared__ short olist[TPB];   // row | (is_mask << 8)
    __shared__ int Ssh, Osh;

    const int tid  = threadIdx.x;
    const int lane = tid & 63;
    const int wave = tid >> 6;

    // XCD-bijective swizzle: consecutive output regions stay on one XCD's L2.
    const int nblk = (int)gridDim.x;
    const int bid  = (int)blockIdx.x;
    const int wg   = ((nblk & 7) == 0) ? ((bid & 7) * (nblk >> 3) + (bid >> 3))
                                       : bid;
    const long t0  = (long)wg * TPB;
    const int nvalid = min(TPB, (int)(T - t0));

    // ---- step 1: masks, survivor + override compaction (wave 0) ----
    if (wave == 0) {
        int o = 3; // out-of-range: neither computed nor written
        if (lane < nvalid) {
            int pm  = pad_mask[t0 + lane];
            int msk = masked_mask[t0 + lane];
            o = msk ? 2 : (pm ? 1 : 0);
            xs[lane] = gene[t0 + lane];
        }
        unsigned long long bs = __ballot(o == 0);
        unsigned long long bo = __ballot(o == 1 || o == 2);
        int si = __popcll(bs & ((1ull << lane) - 1ull));
        int oi = __popcll(bo & ((1ull << lane) - 1ull));
        if (o == 0) surv[si] = (short)lane;
        if (o == 1 || o == 2) olist[oi] = (short)(lane | ((o == 2) ? 256 : 0));
        if (lane == 0) { Ssh = __popcll(bs); Osh = __popcll(bo); }
    }
    __syncthreads();
    const int S = Ssh, O = Osh;

    // ---- step 1.5: override rows, row-per-wave, NT streaming stores ----
    // (r12 A/B: NT = -28 us; keeps 355 MB of pad/mask lines out of L2.)
    {
        const f32x4* pe = (const f32x4*)pad_emb;
        const f32x4* me = (const f32x4*)mask_emb;
        f32x4 p0 = bfrt4(pe[lane]), p1 = bfrt4(pe[lane + 64]), p2 = bfrt4(pe[lane + 128]);
        f32x4 m0 = bfrt4(me[lane]), m1 = bfrt4(me[lane + 64]), m2 = bfrt4(me[lane + 128]);
        for (int i = wave; i < O; i += 4) {
            int e = olist[i];
            int row = e & 63;
            bool mm = (e & 256) != 0;
            f32x4* orow = (f32x4*)(out + (t0 + row) * (long)DIM);
            __builtin_nontemporal_store(mm ? m0 : p0, orow + lane);
            __builtin_nontemporal_store(mm ? m1 : p1, orow + lane + 64);
            __builtin_nontemporal_store(mm ? m2 : p2, orow + lane + 128);
        }
    }

    // ---- steps 2-4 collapsed: v3 = x*P + Q + rare-bin corrections; softmax ----
    // Rare walk: ONE float4 load per iteration (packed {t,w1,b1,k}); correction
    // row w2pT[k][j0..j0+24] is CONTIGUOUS (4-lane group covers 400B span).
    {
        int s = wave + 4 * (lane >> 2);
        int part = lane & 3;
        const int j0 = part * 25;
        if (s < S) {
            float x = xs[surv[s]];
            float v3[25];
            #pragma unroll
            for (int i = 0; i < 25; i++)
                v3[i] = fmaf(x, Pv[j0 + i], Qv[j0 + i]);
            const int R = *Rp;
            for (int idx = 0; idx < R; ++idx) {
                f32x4 rr = rare[idx];
                if (rr.x <= x) break;           // sorted desc: rest are common
                float v1 = fmaf(x, rr.y, rr.z);
                float d = 0.9f * fabsf(v1);     // (f_actual - f_common)*v1
                int k = __float_as_int(rr.w);
                const float* wc = w2pT + k * BINS + j0;
                #pragma unroll
                for (int i = 0; i < 25; i++)
                    v3[i] = fmaf(wc[i], d, v3[i]);
            }
            float vmax = -1e30f;
            #pragma unroll
            for (int i = 0; i < 25; i++) vmax = fmaxf(vmax, v3[i]);
            vmax = fmaxf(vmax, __shfl_xor(vmax, 1));
            vmax = fmaxf(vmax, __shfl_xor(vmax, 2));
            float sum = 0.f;
            #pragma unroll
            for (int i = 0; i < 25; i++) {
                v3[i] = __expf(v3[i] - vmax);
                sum += v3[i];
            }
            sum += __shfl_xor(sum, 1);
            sum += __shfl_xor(sum, 2);
            float inv = 1.f / sum;
            #pragma unroll
            for (int i = 0; i < 25; i++)
                wbf[s][j0 + i] = f2bf(v3[i] * inv);
            if (part == 3) {
                #pragma unroll
                for (int j = BINS; j < KPAD; j += 2)
                    *reinterpret_cast<unsigned int*>(&wbf[s][j]) = 0u;
            }
        }
    }
    __syncthreads();

    // ---- step 5: MFMA 32x32x16: D[slot][d] = W(S x K) · ET^T(K x d) ----
    // C/D layout (verified): col=lane&31, row=(reg&3)+8*(reg>>2)+4*(lane>>5).
    // A,B share k-mapping k = ks*16 + half*8 + j (hw k-perm cancels).
    // One store instruction = 2 rows x 128B fully-covered lines -> NT-safe.
    // THIS ROUND'S SINGLE CHANGE: survivor stores also nontemporal (uniform
    // no-allocate write stream; survivor lines stop evicting et/w2pT from L2).
    if (S > 0) {
        const int col  = lane & 31;
        const int half = lane >> 5;
        const int nmt = (S > 32) ? 2 : 1;
        for (int mtile = 0; mtile < nmt; mtile++) {
            const unsigned short* arow = &wbf[mtile * 32 + col][half * 8];
            bf16x8 a0 = *(const bf16x8*)(arow);
            bf16x8 a1 = *(const bf16x8*)(arow + 16);
            bf16x8 a2 = *(const bf16x8*)(arow + 32);
            bf16x8 a3 = *(const bf16x8*)(arow + 48);
            bf16x8 a4 = *(const bf16x8*)(arow + 64);
            bf16x8 a5 = *(const bf16x8*)(arow + 80);
            bf16x8 a6 = *(const bf16x8*)(arow + 96);
            bf16x8 a7 = *(const bf16x8*)(arow + 112);
            for (int ct = 0; ct < 6; ct++) {
                int cbase = (wave * 6 + ct) * 32;
                const unsigned short* bp = et + (long)(cbase + col) * KPAD + half * 8;
                f32x16 acc;
                #pragma unroll
                for (int r = 0; r < 16; r++) acc[r] = 0.f;
                acc = __builtin_amdgcn_mfma_f32_32x32x16_bf16(a0, *(const bf16x8*)(bp),       acc, 0, 0, 0);
                acc = __builtin_amdgcn_mfma_f32_32x32x16_bf16(a1, *(const bf16x8*)(bp + 16),  acc, 0, 0, 0);
                acc = __builtin_amdgcn_mfma_f32_32x32x16_bf16(a2, *(const bf16x8*)(bp + 32),  acc, 0, 0, 0);
                acc = __builtin_amdgcn_mfma_f32_32x32x16_bf16(a3, *(const bf16x8*)(bp + 48),  acc, 0, 0, 0);
                acc = __builtin_amdgcn_mfma_f32_32x32x16_bf16(a4, *(const bf16x8*)(bp + 64),  acc, 0, 0, 0);
                acc = __builtin_amdgcn_mfma_f32_32x32x16_bf16(a5, *(const bf16x8*)(bp + 80),  acc, 0, 0, 0);
                acc = __builtin_amdgcn_mfma_f32_32x32x16_bf16(a6, *(const bf16x8*)(bp + 96),  acc, 0, 0, 0);
                acc = __builtin_amdgcn_mfma_f32_32x32x16_bf16(a7, *(const bf16x8*)(bp + 112), acc, 0, 0, 0);
                #pragma unroll
                for (int r = 0; r < 16; r++) {
                    int row = (r & 3) + 8 * (r >> 2) + 4 * half + mtile * 32;
                    if (row < S) {
                        int tkn = surv[row];
                        __builtin_nontemporal_store(
                            acc[r], out + (t0 + tkn) * (long)DIM + cbase + col);
                    }
                }
            }
        }
    }
}

extern "C" void kernel_launch(void* const* d_in, const int* in_sizes, int n_in,
                              void* d_out, int out_size, void* d_ws, size_t ws_size,
                              hipStream_t stream) {
    const float* gene  = (const float*)d_in[0];
    const int*   pm    = (const int*)  d_in[1];
    const int*   mm    = (const int*)  d_in[2];
    const float* w1    = (const float*)d_in[3];
    const float* b1    = (const float*)d_in[4];
    const float* w2    = (const float*)d_in[5];
    const float* b2    = (const float*)d_in[6];
    const float* emb   = (const float*)d_in[7];
    const float* pade  = (const float*)d_in[8];
    const float* maske = (const float*)d_in[9];
    float* out = (float*)d_out;
    unsigned char* ws = (unsigned char*)d_ws;

    int T = in_sizes[0];                          // 8 * 19264 = 154112 tokens
    int nblk = (T + TPB - 1) / TPB;               // 2408 (divisible by 8)

    hipLaunchKernelGGL(prep, dim3(DIM + BINS), dim3(128), 0, stream,
                       emb, w1, b1, w2, b2, ws);
    hipLaunchKernelGGL(ead_kernel, dim3(nblk), dim3(NTHREADS), 0, stream,
                       gene, pm, mm,
                       (const unsigned short*)(ws + OFF_ET),
                       (const float*)(ws + OFF_P),
                       (const float*)(ws + OFF_Q),
                       (const f32x4*)(ws + OFF_RARE),
                       (const int*)(ws + OFF_R),
                       (const float*)(ws + OFF_W2PT),
                       pade, maske, out, T);
}